// Round 1
// baseline (256.211 us; speedup 1.0000x reference)
//
#include <hip/hip_runtime.h>

// Problem constants (match reference setup_inputs)
#define N_  8
#define K_  8
#define H_  512
#define W_  512
#define C_  4
#define P_  100000

__global__ __launch_bounds__(256) void alpha_composite_kernel(
    const int*   __restrict__ pix_idxs,   // [N,K,H,W]
    const float* __restrict__ alphas,     // [N,K,H,W]
    const float* __restrict__ ptclds,     // [C,P]
    float*       __restrict__ out)        // images [N,C,H,W] then mask [N,H,W]
{
    const int HW   = H_ * W_;
    const int NPIX = N_ * HW;
    float* __restrict__ out_img  = out;
    float* __restrict__ out_mask = out + (size_t)N_ * C_ * HW;

    const int stride = gridDim.x * blockDim.x;
    for (int p = blockIdx.x * blockDim.x + threadIdx.x; p < NPIX; p += stride) {
        const int n  = p / HW;
        const int hw = p - n * HW;
        const int base = n * K_ * HW + hw;   // k=0 plane element

        const int idx0 = pix_idxs[base];
        const bool fg  = (idx0 >= 0);

        float t = 1.0f;
        float acc0 = 0.0f, acc1 = 0.0f, acc2 = 0.0f, acc3 = 0.0f;

        #pragma unroll
        for (int k = 0; k < K_; ++k) {
            const int   idx = (k == 0) ? idx0 : pix_idxs[base + k * HW];
            const float al  = alphas[base + k * HW];
            // invalid (idx<0) entries: zero alpha == skip (padding is trailing)
            const float a  = (idx >= 0) ? al : 0.0f;
            const int   gi = (idx >= 0) ? idx : 0;
            const float w  = a * t;
            t *= (1.0f - a);
            acc0 += w * ptclds[gi];
            acc1 += w * ptclds[gi + P_];
            acc2 += w * ptclds[gi + 2 * P_];
            acc3 += w * ptclds[gi + 3 * P_];
        }

        if (!fg) {
            // background color (0,0,0,1); acc0..2 already 0 since all weights 0
            acc0 = 0.0f; acc1 = 0.0f; acc2 = 0.0f; acc3 = 1.0f;
        }

        const int ob = n * C_ * HW + hw;
        out_img[ob]          = acc0;
        out_img[ob + HW]     = acc1;
        out_img[ob + 2 * HW] = acc2;
        out_img[ob + 3 * HW] = acc3;
        out_mask[n * HW + hw] = fg ? 1.0f : 0.0f;
    }
}

extern "C" void kernel_launch(void* const* d_in, const int* in_sizes, int n_in,
                              void* d_out, int out_size, void* d_ws, size_t ws_size,
                              hipStream_t stream) {
    const int*   pix_idxs = (const int*)  d_in[0];
    const float* alphas   = (const float*)d_in[1];
    const float* ptclds   = (const float*)d_in[2];
    float*       out      = (float*)d_out;

    const int threads = 256;
    const int blocks  = 2048;   // grid-stride over 2,097,152 pixels (4 px/thread)
    alpha_composite_kernel<<<blocks, threads, 0, stream>>>(pix_idxs, alphas, ptclds, out);
}

// Round 2
// 84.068 us; speedup vs baseline: 3.0477x; 3.0477x over previous
//
#include <hip/hip_runtime.h>

// Problem constants (match reference setup_inputs)
#define N_  8
#define K_  8
#define H_  512
#define W_  512
#define C_  4
#define P_  100000

// ---------------------------------------------------------------------------
// Pre-pass: transpose ptclds [C,P] -> [P] float4 so each point gather is one
// 16B access instead of four 4B accesses 400KB apart.
// ---------------------------------------------------------------------------
__global__ __launch_bounds__(256) void transpose_ptclds_kernel(
    const float* __restrict__ ptclds,   // [C,P]
    float4*      __restrict__ pt)       // [P]
{
    const int i = blockIdx.x * blockDim.x + threadIdx.x;
    if (i < P_) {
        float4 v;
        v.x = ptclds[i];
        v.y = ptclds[i + P_];
        v.z = ptclds[i + 2 * P_];
        v.w = ptclds[i + 3 * P_];
        pt[i] = v;
    }
}

// ---------------------------------------------------------------------------
// Main kernel: 4 consecutive pixels per thread. Streaming loads/stores are
// int4/float4; per-(pixel,k) point fetch is one float4 gather.
// ---------------------------------------------------------------------------
__global__ __launch_bounds__(256) void composite4_kernel(
    const int*    __restrict__ pix_idxs,  // [N,K,H,W]
    const float*  __restrict__ alphas,    // [N,K,H,W]
    const float4* __restrict__ pt,        // [P] transposed features
    float*        __restrict__ out)       // images [N,C,H,W] then mask [N,H,W]
{
    const int HW = H_ * W_;
    float* __restrict__ out_img  = out;
    float* __restrict__ out_mask = out + (size_t)N_ * C_ * HW;

    const int tid = blockIdx.x * blockDim.x + threadIdx.x;
    const int p4  = tid * 4;                 // first of 4 consecutive pixels
    if (p4 >= N_ * HW) return;
    const int n    = p4 / HW;                // HW%4==0 -> all 4 px same n
    const int hw   = p4 - n * HW;
    const int base = n * K_ * HW + hw;       // 16B-aligned (hw%4==0)

    // Stage all streaming input (8 int4 + 8 float4 = 16 dwordx4 loads)
    int4   idx[K_];
    float4 al[K_];
    #pragma unroll
    for (int k = 0; k < K_; ++k) {
        idx[k] = *reinterpret_cast<const int4*>(pix_idxs + base + k * HW);
        al[k]  = *reinterpret_cast<const float4*>(alphas + base + k * HW);
    }

    float acc[4][4] = {};                    // [px][ch], static indices only
    float t0 = 1.f, t1 = 1.f, t2 = 1.f, t3 = 1.f;

    #pragma unroll
    for (int k = 0; k < K_; ++k) {
        // pixel 0
        {
            const int   id = idx[k].x;
            const float a  = (id >= 0) ? al[k].x : 0.f;
            const float w  = a * t0;  t0 *= (1.f - a);
            const float4 f = pt[(id >= 0) ? id : 0];
            acc[0][0] += w * f.x; acc[0][1] += w * f.y;
            acc[0][2] += w * f.z; acc[0][3] += w * f.w;
        }
        // pixel 1
        {
            const int   id = idx[k].y;
            const float a  = (id >= 0) ? al[k].y : 0.f;
            const float w  = a * t1;  t1 *= (1.f - a);
            const float4 f = pt[(id >= 0) ? id : 0];
            acc[1][0] += w * f.x; acc[1][1] += w * f.y;
            acc[1][2] += w * f.z; acc[1][3] += w * f.w;
        }
        // pixel 2
        {
            const int   id = idx[k].z;
            const float a  = (id >= 0) ? al[k].z : 0.f;
            const float w  = a * t2;  t2 *= (1.f - a);
            const float4 f = pt[(id >= 0) ? id : 0];
            acc[2][0] += w * f.x; acc[2][1] += w * f.y;
            acc[2][2] += w * f.z; acc[2][3] += w * f.w;
        }
        // pixel 3
        {
            const int   id = idx[k].w;
            const float a  = (id >= 0) ? al[k].w : 0.f;
            const float w  = a * t3;  t3 *= (1.f - a);
            const float4 f = pt[(id >= 0) ? id : 0];
            acc[3][0] += w * f.x; acc[3][1] += w * f.y;
            acc[3][2] += w * f.z; acc[3][3] += w * f.w;
        }
    }

    // Background pixels: entire list invalid -> acc already 0; color=(0,0,0,1)
    const bool fg0 = idx[0].x >= 0, fg1 = idx[0].y >= 0,
               fg2 = idx[0].z >= 0, fg3 = idx[0].w >= 0;
    if (!fg0) acc[0][3] = 1.f;
    if (!fg1) acc[1][3] = 1.f;
    if (!fg2) acc[2][3] = 1.f;
    if (!fg3) acc[3][3] = 1.f;

    const int ob = n * C_ * HW + hw;
    #pragma unroll
    for (int c = 0; c < C_; ++c) {
        float4 o = make_float4(acc[0][c], acc[1][c], acc[2][c], acc[3][c]);
        *reinterpret_cast<float4*>(out_img + ob + c * HW) = o;
    }
    float4 m = make_float4(fg0 ? 1.f : 0.f, fg1 ? 1.f : 0.f,
                           fg2 ? 1.f : 0.f, fg3 ? 1.f : 0.f);
    *reinterpret_cast<float4*>(out_mask + n * HW + hw) = m;
}

// ---------------------------------------------------------------------------
// Fallback (no workspace): same 4-px structure but gathers from [C,P] layout.
// ---------------------------------------------------------------------------
__global__ __launch_bounds__(256) void composite4_noT_kernel(
    const int*   __restrict__ pix_idxs,
    const float* __restrict__ alphas,
    const float* __restrict__ ptclds,    // [C,P]
    float*       __restrict__ out)
{
    const int HW = H_ * W_;
    float* __restrict__ out_img  = out;
    float* __restrict__ out_mask = out + (size_t)N_ * C_ * HW;

    const int tid = blockIdx.x * blockDim.x + threadIdx.x;
    const int p4  = tid * 4;
    if (p4 >= N_ * HW) return;
    const int n    = p4 / HW;
    const int hw   = p4 - n * HW;
    const int base = n * K_ * HW + hw;

    int4   idx[K_];
    float4 al[K_];
    #pragma unroll
    for (int k = 0; k < K_; ++k) {
        idx[k] = *reinterpret_cast<const int4*>(pix_idxs + base + k * HW);
        al[k]  = *reinterpret_cast<const float4*>(alphas + base + k * HW);
    }

    float acc[4][4] = {};
    float t[4] = {1.f, 1.f, 1.f, 1.f};

    #pragma unroll
    for (int k = 0; k < K_; ++k) {
        const int ids[4] = {idx[k].x, idx[k].y, idx[k].z, idx[k].w};
        const float als[4] = {al[k].x, al[k].y, al[k].z, al[k].w};
        #pragma unroll
        for (int px = 0; px < 4; ++px) {
            const int   id = ids[px];
            const float a  = (id >= 0) ? als[px] : 0.f;
            const float w  = a * t[px];  t[px] *= (1.f - a);
            const int   gi = (id >= 0) ? id : 0;
            acc[px][0] += w * ptclds[gi];
            acc[px][1] += w * ptclds[gi + P_];
            acc[px][2] += w * ptclds[gi + 2 * P_];
            acc[px][3] += w * ptclds[gi + 3 * P_];
        }
    }

    const bool fg0 = idx[0].x >= 0, fg1 = idx[0].y >= 0,
               fg2 = idx[0].z >= 0, fg3 = idx[0].w >= 0;
    if (!fg0) acc[0][3] = 1.f;
    if (!fg1) acc[1][3] = 1.f;
    if (!fg2) acc[2][3] = 1.f;
    if (!fg3) acc[3][3] = 1.f;

    const int ob = n * C_ * HW + hw;
    #pragma unroll
    for (int c = 0; c < C_; ++c) {
        float4 o = make_float4(acc[0][c], acc[1][c], acc[2][c], acc[3][c]);
        *reinterpret_cast<float4*>(out_img + ob + c * HW) = o;
    }
    float4 m = make_float4(fg0 ? 1.f : 0.f, fg1 ? 1.f : 0.f,
                           fg2 ? 1.f : 0.f, fg3 ? 1.f : 0.f);
    *reinterpret_cast<float4*>(out_mask + n * HW + hw) = m;
}

extern "C" void kernel_launch(void* const* d_in, const int* in_sizes, int n_in,
                              void* d_out, int out_size, void* d_ws, size_t ws_size,
                              hipStream_t stream) {
    const int*   pix_idxs = (const int*)  d_in[0];
    const float* alphas   = (const float*)d_in[1];
    const float* ptclds   = (const float*)d_in[2];
    float*       out      = (float*)d_out;

    const int HW      = H_ * W_;
    const int threads = 256;
    const int nthread = N_ * HW / 4;             // 4 px per thread
    const int blocks  = (nthread + threads - 1) / threads;   // 2048

    const size_t t_bytes = (size_t)P_ * sizeof(float4);      // 1.6 MB
    if (ws_size >= t_bytes) {
        float4* pt = (float4*)d_ws;
        transpose_ptclds_kernel<<<(P_ + threads - 1) / threads, threads, 0, stream>>>(
            ptclds, pt);
        composite4_kernel<<<blocks, threads, 0, stream>>>(pix_idxs, alphas, pt, out);
    } else {
        composite4_noT_kernel<<<blocks, threads, 0, stream>>>(pix_idxs, alphas, ptclds, out);
    }
}